// Round 1
// baseline (1514.103 us; speedup 1.0000x reference)
//
#include <hip/hip_runtime.h>
#include <hip/hip_bf16.h>

typedef float f32x4 __attribute__((ext_vector_type(4)));
typedef __bf16 bf16x8 __attribute__((ext_vector_type(8)));
typedef unsigned short u16x8 __attribute__((ext_vector_type(8)));

#define B_ 32
#define N_ 8192
#define D_ 1024
#define H_ 128

__device__ __forceinline__ unsigned short f2bf(float f) {
  unsigned u = __builtin_bit_cast(unsigned, f);
  u += 0x7fffu + ((u >> 16) & 1u);   // RNE
  return (unsigned short)(u >> 16);
}

// ---- Kernel 0: w1 [D][H] fp32 -> w1t [H][D] bf16 (transpose + convert) ----
__global__ void k_w1t(const float* __restrict__ w1, unsigned short* __restrict__ w1t) {
  int h = blockIdx.x;
  for (int k = threadIdx.x; k < D_; k += blockDim.x)
    w1t[h * D_ + k] = f2bf(w1[k * H_ + h]);
}

// ---- Kernel A: s[token] = sum_h tanh(feats.W1 + b1)*w2  (bf16 MFMA GEMM) ----
// Block: 128 tokens x 128 H, BK=64, 4 waves (each 32 rows x 128 cols).
__global__ __launch_bounds__(256) void k_scores(
    const float* __restrict__ feats, const unsigned short* __restrict__ w1t,
    const float* __restrict__ b1, const float* __restrict__ w2,
    float* __restrict__ s_out)
{
  __shared__ unsigned short lds_a[128 * 72];   // rows padded 64->72 (16B-aligned, conflict-free)
  __shared__ unsigned short lds_b[128 * 64];   // W1^T tile, 16B-granule XOR swizzle
  __shared__ float b1s[H_], w2s[H_];
  const int tid = threadIdx.x;
  const int lane = tid & 63;
  const int w = tid >> 6;
  const long tb = (long)blockIdx.x * 128;

  if (tid < H_) { b1s[tid] = b1[tid]; w2s[tid] = w2[tid]; }

  f32x4 acc[2][8];
#pragma unroll
  for (int i = 0; i < 2; ++i)
#pragma unroll
    for (int j = 0; j < 8; ++j) acc[i][j] = (f32x4){0.f, 0.f, 0.f, 0.f};

  const int r0 = tid >> 3;          // 0..31
  const int kc = (tid & 7) * 8;     // 0,8,..,56

  for (int kt = 0; kt < 16; ++kt) {
    const int k0 = kt * 64;
    // --- B tile: async global->LDS, 16B/lane, wave-uniform LDS base + lane*16.
    // LDS position p (0..7) of row n holds global granule p^(n&7) (XOR swizzle).
#pragma unroll
    for (int c = 0; c < 4; ++c) {
      int n = 32 * w + 8 * c + (lane >> 3);
      int sg = (lane & 7) ^ (n & 7);
      const unsigned short* g = w1t + (long)n * D_ + k0 + sg * 8;
      __builtin_amdgcn_global_load_lds(
          (const __attribute__((address_space(1))) void*)g,
          (__attribute__((address_space(3))) void*)(lds_b + (32 * w + 8 * c) * 64),
          16, 0, 0);
    }
    // --- A tile: fp32 -> bf16 -> LDS (padded rows) ---
#pragma unroll
    for (int s = 0; s < 4; ++s) {
      int r = r0 + 32 * s;
      const float* src = feats + (tb + r) * (long)D_ + k0 + kc;
      float4 f0 = *(const float4*)src;
      float4 f1 = *(const float4*)(src + 4);
      u16x8 v;
      v[0] = f2bf(f0.x); v[1] = f2bf(f0.y); v[2] = f2bf(f0.z); v[3] = f2bf(f0.w);
      v[4] = f2bf(f1.x); v[5] = f2bf(f1.y); v[6] = f2bf(f1.z); v[7] = f2bf(f1.w);
      *(u16x8*)&lds_a[r * 72 + kc] = v;
    }
    __syncthreads();
    // --- MFMA: 2 row-tiles x 8 col-tiles x 2 k-steps ---
#pragma unroll
    for (int ks = 0; ks < 2; ++ks) {
      bf16x8 af[2], bfr[8];
      const int rin = lane & 15;
      const int kg = ks * 32 + (lane >> 4) * 8;
#pragma unroll
      for (int i = 0; i < 2; ++i)
        af[i] = __builtin_bit_cast(bf16x8,
                  *(const u16x8*)&lds_a[(32 * w + 16 * i + rin) * 72 + kg]);
      const int gq = ks * 4 + (lane >> 4);
#pragma unroll
      for (int j = 0; j < 8; ++j) {
        int n = 16 * j + rin;
        bfr[j] = __builtin_bit_cast(bf16x8,
                   *(const u16x8*)&lds_b[n * 64 + ((gq ^ (n & 7)) * 8)]);
      }
#pragma unroll
      for (int i = 0; i < 2; ++i)
#pragma unroll
        for (int j = 0; j < 8; ++j)
          acc[i][j] = __builtin_amdgcn_mfma_f32_16x16x32_bf16(af[i], bfr[j], acc[i][j], 0, 0, 0);
    }
    __syncthreads();
  }

  // --- epilogue: tanh + dot(w2) + 16-lane reduce; C/D: col=lane&15, row=(lane>>4)*4+reg ---
  const int colb = lane & 15;
  const int g4 = lane >> 4;
#pragma unroll
  for (int i = 0; i < 2; ++i) {
#pragma unroll
    for (int r = 0; r < 4; ++r) {
      float p = 0.f;
#pragma unroll
      for (int j = 0; j < 8; ++j) {
        int c = 16 * j + colb;
        p += tanhf(acc[i][j][r] + b1s[c]) * w2s[c];
      }
      p += __shfl_xor(p, 1);
      p += __shfl_xor(p, 2);
      p += __shfl_xor(p, 4);
      p += __shfl_xor(p, 8);
      if (colb == 0)
        s_out[tb + 32 * w + 16 * i + 4 * g4 + r] = p;
    }
  }
}

// ---- Kernel B: masked softmax over N per batch ----
__global__ __launch_bounds__(256) void k_softmax(
    const float* __restrict__ s, const int* __restrict__ mask,
    float* __restrict__ attn)
{
  const int b = blockIdx.x;
  const int tid = threadIdx.x;
  const float* sb = s + (long)b * N_;
  const int* mb = mask + (long)b * N_;
  __shared__ float red[4];

  float mx = -3.4e38f;
  for (int n = tid; n < N_; n += 256) if (mb[n]) mx = fmaxf(mx, sb[n]);
#pragma unroll
  for (int o = 32; o > 0; o >>= 1) mx = fmaxf(mx, __shfl_xor(mx, o));
  if ((tid & 63) == 0) red[tid >> 6] = mx;
  __syncthreads();
  mx = fmaxf(fmaxf(red[0], red[1]), fmaxf(red[2], red[3]));
  __syncthreads();

  float sum = 0.f;
  for (int n = tid; n < N_; n += 256) if (mb[n]) sum += expf(sb[n] - mx);
#pragma unroll
  for (int o = 32; o > 0; o >>= 1) sum += __shfl_xor(sum, o);
  if ((tid & 63) == 0) red[tid >> 6] = sum;
  __syncthreads();
  sum = red[0] + red[1] + red[2] + red[3];
  float inv = sum > 0.f ? 1.f / sum : 0.f;   // all-masked batch -> zeros

  for (int n = tid; n < N_; n += 256)
    attn[(long)b * N_ + n] = mb[n] ? expf(sb[n] - mx) * inv : 0.f;
}

// ---- Kernel C: pooled[b,:] += sum_n attn[b,n]*feats[b,n,:], skipping attn==0 rows ----
__global__ __launch_bounds__(256) void k_pool(
    const float* __restrict__ feats, const float* __restrict__ attn,
    float* __restrict__ pooled)
{
  const int chunk = blockIdx.x;    // 32 chunks of 256 rows
  const int b = blockIdx.y;
  const int tid = threadIdx.x;
  const int n0 = chunk * 256;
  __shared__ float a_s[256];
  a_s[tid] = attn[(long)b * N_ + n0 + tid];
  __syncthreads();
  float4 acc = {0.f, 0.f, 0.f, 0.f};
  const float* fb = feats + ((long)b * N_ + n0) * D_ + tid * 4;
  for (int i = 0; i < 256; ++i) {
    float a = a_s[i];
    if (a != 0.f) {                 // block-uniform branch: masked rows never loaded
      float4 f = *(const float4*)(fb + (long)i * D_);
      acc.x += a * f.x; acc.y += a * f.y; acc.z += a * f.z; acc.w += a * f.w;
    }
  }
  float* pb = pooled + b * D_ + tid * 4;
  atomicAdd(pb + 0, acc.x);
  atomicAdd(pb + 1, acc.y);
  atomicAdd(pb + 2, acc.z);
  atomicAdd(pb + 3, acc.w);
}

// ---- Kernel D: logits[b] = pooled[b,:].wc + bc ----
__global__ __launch_bounds__(256) void k_logits(
    const float* __restrict__ pooled, const float* __restrict__ wc,
    const float* __restrict__ bc, float* __restrict__ logits)
{
  const int b = blockIdx.x;
  const int tid = threadIdx.x;
  float p = 0.f;
  for (int k = tid; k < D_; k += 256) p += pooled[b * D_ + k] * wc[k];
#pragma unroll
  for (int o = 32; o > 0; o >>= 1) p += __shfl_xor(p, o);
  __shared__ float red[4];
  if ((tid & 63) == 0) red[tid >> 6] = p;
  __syncthreads();
  if (tid == 0) logits[b] = red[0] + red[1] + red[2] + red[3] + bc[0];
}

extern "C" void kernel_launch(void* const* d_in, const int* in_sizes, int n_in,
                              void* d_out, int out_size, void* d_ws, size_t ws_size,
                              hipStream_t stream) {
  const float* feats = (const float*)d_in[0];
  const int* mask    = (const int*)d_in[1];    // jnp.bool_ assumed delivered as int32
  const float* w1    = (const float*)d_in[2];
  const float* b1    = (const float*)d_in[3];
  const float* w2    = (const float*)d_in[4];
  // d_in[5] = b2: unused — softmax is shift-invariant, so b2 cannot affect any output
  const float* wc    = (const float*)d_in[6];
  const float* bc    = (const float*)d_in[7];

  float* logits = (float*)d_out;                     // [32]
  float* pooled = (float*)d_out + 32;                // [32,1024]
  float* attn   = (float*)d_out + 32 + B_ * D_;      // [32,8192]

  unsigned short* w1t = (unsigned short*)d_ws;                   // 128*1024 bf16
  float* s = (float*)((char*)d_ws + (size_t)H_ * D_ * 2);        // 262144 fp32 scores

  k_w1t<<<H_, 256, 0, stream>>>(w1, w1t);
  k_scores<<<(B_ * N_) / 128, 256, 0, stream>>>(feats, w1t, b1, w2, s);
  k_softmax<<<B_, 256, 0, stream>>>(s, mask, attn);
  hipMemsetAsync(pooled, 0, (size_t)B_ * D_ * sizeof(float), stream);
  k_pool<<<dim3(32, B_), 256, 0, stream>>>(feats, attn, pooled);
  k_logits<<<B_, 256, 0, stream>>>(pooled, wc, bc, logits);
}